// Round 5
// baseline (296.186 us; speedup 1.0000x reference)
//
#include <hip/hip_runtime.h>

typedef unsigned short u16;
typedef unsigned int u32;
typedef __bf16 bf16x8 __attribute__((ext_vector_type(8)));
typedef float f32x4 __attribute__((ext_vector_type(4)));
typedef u16 u16x8 __attribute__((ext_vector_type(8)));

#define SC2 0.18033688011112042f /* 0.125 * log2(e) */

__device__ __forceinline__ u16 bf16rne(float f) {
  u32 u = __float_as_uint(f);
  u32 r = (u + 0x7FFFu + ((u >> 16) & 1u)) >> 16;
  return (u16)r;
}
__device__ __forceinline__ u32 packrne(float a, float b) {
  return (u32)bf16rne(a) | ((u32)bf16rne(b) << 16);
}
__device__ __forceinline__ float b2f(u16 v) {
  return __uint_as_float(((u32)v) << 16);
}

__device__ __forceinline__ void async16(const void* g, void* l) {
  __builtin_amdgcn_global_load_lds(
      (__attribute__((address_space(1))) void*)(g),
      (__attribute__((address_space(3))) void*)(l), 16, 0, 0);
}
template <int N>
__device__ __forceinline__ void vm_wait() {
  asm volatile("s_waitcnt vmcnt(%0)" ::"n"(N) : "memory");
}
__device__ __forceinline__ void lgkm_wait0() {
  asm volatile("s_waitcnt lgkmcnt(0)" ::: "memory");
}
__device__ __forceinline__ void bar() {
  asm volatile("s_barrier" ::: "memory");
}

// ---------------- layernorm body (one wave per 512-row)
__device__ __forceinline__ void ln_row(const float* xr, const float* gp,
                                       const float* bp, u16* orow, int lane) {
  const float* xl = xr + lane * 8;
  float4 a0 = *(const float4*)xl;
  float4 a1 = *(const float4*)(xl + 4);
  float v[8] = {a0.x, a0.y, a0.z, a0.w, a1.x, a1.y, a1.z, a1.w};
  float s = 0.f, s2 = 0.f;
#pragma unroll
  for (int j = 0; j < 8; ++j) { s += v[j]; s2 += v[j] * v[j]; }
#pragma unroll
  for (int off = 32; off; off >>= 1) {
    s += __shfl_xor(s, off);
    s2 += __shfl_xor(s2, off);
  }
  float mu = s * (1.0f / 512.0f);
  float rstd = rsqrtf(s2 * (1.0f / 512.0f) - mu * mu + 1e-5f);
  const float* gl = gp + lane * 8;
  const float* bl = bp + lane * 8;
  float4 g0 = *(const float4*)gl, g1 = *(const float4*)(gl + 4);
  float4 b0 = *(const float4*)bl, b1 = *(const float4*)(bl + 4);
  float gg[8] = {g0.x, g0.y, g0.z, g0.w, g1.x, g1.y, g1.z, g1.w};
  float bb[8] = {b0.x, b0.y, b0.z, b0.w, b1.x, b1.y, b1.z, b1.w};
  u16x8 ov;
#pragma unroll
  for (int j = 0; j < 8; ++j) ov[j] = bf16rne((v[j] - mu) * rstd * gg[j] + bb[j]);
  *(u16x8*)(orow + lane * 8) = ov;
}

// ---------------- prep: blocks 0..383 = weight transpose (6 x 64 tiles),
// blocks 384..4479 = merged LN of q0 (rows<8192) and kv0
__global__ __launch_bounds__(256) void prep_kernel(
    const float* __restrict__ w0, const float* __restrict__ w1,
    const float* __restrict__ w2, const float* __restrict__ w3,
    const float* __restrict__ w4, const float* __restrict__ w5,
    u16* __restrict__ wout,
    const float* __restrict__ x0, const float* __restrict__ g0,
    const float* __restrict__ b0, u16* __restrict__ o0,
    const float* __restrict__ x1, const float* __restrict__ g1,
    const float* __restrict__ b1, u16* __restrict__ o1) {
  __shared__ u16 T[64 * 72];
  int t = threadIdx.x;
  int bx = blockIdx.x;
  if (bx < 384) {
    int widx = bx >> 6, tile = bx & 63;
    int k0 = (tile & 7) * 64, n0 = (tile >> 3) * 64;
    const float* W = w0;
    if (widx == 1) W = w1; else if (widx == 2) W = w2; else if (widx == 3) W = w3;
    else if (widx == 4) W = w4; else if (widx == 5) W = w5;
#pragma unroll
    for (int p = 0; p < 4; ++p) {
      int kr = p * 16 + (t >> 4);
      int nc = (t & 15) * 4;
      float4 v = *(const float4*)(W + (size_t)(k0 + kr) * 512 + n0 + nc);
      T[(nc + 0) * 72 + kr] = bf16rne(v.x);
      T[(nc + 1) * 72 + kr] = bf16rne(v.y);
      T[(nc + 2) * 72 + kr] = bf16rne(v.z);
      T[(nc + 3) * 72 + kr] = bf16rne(v.w);
    }
    __syncthreads();
    u16* ob = wout + (size_t)widx * 262144;
#pragma unroll
    for (int p = 0; p < 2; ++p) {
      int idx = p * 256 + t;
      int nr = idx >> 3, ch = idx & 7;
      uint4 val = *(const uint4*)(T + nr * 72 + ch * 8);
      *(uint4*)(ob + (size_t)(n0 + nr) * 512 + k0 + ch * 8) = val;
    }
  } else {
    int w = t >> 6, lane = t & 63;
    size_t row = (size_t)(bx - 384) * 4 + w;
    if (row < 8192) {
      ln_row(x0 + row * 512, g0, b0, o0 + row * 512, lane);
    } else {
      size_t r2 = row - 8192;
      ln_row(x1 + r2 * 512, g1, b1, o1 + r2 * 512, lane);
    }
  }
}

__global__ __launch_bounds__(256) void ln_kernel(
    const float* __restrict__ x, const float* __restrict__ g,
    const float* __restrict__ b, u16* __restrict__ o) {
  int w = threadIdx.x >> 6, lane = threadIdx.x & 63;
  size_t row = (size_t)blockIdx.x * 4 + w;
  ln_row(x + row * 512, g, b, o + row * 512, lane);
}

// shared staging macro: 128x32 A-tile + 64x32 B-tile, 3 DMAs/thread
#define GSTAGE(buf, k0)                                                          \
  {                                                                              \
    _Pragma("unroll") for (int i = 0; i < 2; ++i) {                              \
      int s = t + 256 * i;                                                       \
      int mts = s >> 6, L = s & 63;                                             \
      async16(A + (size_t)(row0 + mts * 16 + (L & 15)) * 512 + (k0) + (L >> 4) * 8, \
              (char*)As[buf] + s * 16);                                          \
    }                                                                            \
    {                                                                            \
      int s = t;                                                                 \
      int nts = s >> 6, L = s & 63;                                             \
      async16(Bt + (size_t)(col0 + nts * 16 + (L & 15)) * 512 + (k0) + (L >> 4) * 8, \
              (char*)Bs[buf] + s * 16);                                          \
    }                                                                            \
  }

// 4-deep pipelined K-loop (prefetch 3 tiles, 1 barrier/iter) + 8 MFMAs/wave
#define GEMM_CORE                                                                \
  GSTAGE(0, 0);                                                                  \
  GSTAGE(1, 32);                                                                 \
  GSTAGE(2, 64);                                                                 \
  _Pragma("unroll") for (int kk = 0; kk < 16; ++kk) {                            \
    if (kk <= 13) vm_wait<6>();                                                  \
    else if (kk == 14) vm_wait<3>();                                             \
    else vm_wait<0>();                                                           \
    bar();                                                                       \
    if (kk < 13) GSTAGE((kk + 3) & 3, (kk + 3) * 32);                            \
    const u16* Ac = As[kk & 3];                                                  \
    const u16* Bc = Bs[kk & 3];                                                  \
    bf16x8 Af[2], Bf[4];                                                         \
    _Pragma("unroll") for (int mt = 0; mt < 2; ++mt)                             \
        Af[mt] = *(const bf16x8*)(Ac + ((w * 2 + mt) * 64 + lane) * 8);          \
    _Pragma("unroll") for (int nt = 0; nt < 4; ++nt)                             \
        Bf[nt] = *(const bf16x8*)(Bc + (nt * 64 + lane) * 8);                    \
    _Pragma("unroll") for (int mt = 0; mt < 2; ++mt)                             \
        _Pragma("unroll") for (int nt = 0; nt < 4; ++nt)                         \
            acc[mt][nt] = __builtin_amdgcn_mfma_f32_16x16x32_bf16(               \
                Af[mt], Bf[nt], acc[mt][nt], 0, 0, 0);                           \
  }

// ---------------- GEMM: C[8192,512] = A[8192,512](bf16) @ Bt[n][k](bf16)
// 128x64 tile, 4 waves. MODE 1: f32+res; 2: +bias relu bf16; 3: +bias+res f32
template <int MODE>
__global__ __launch_bounds__(256) void gemm512_kernel(
    const u16* __restrict__ A, const u16* __restrict__ Bt, void* __restrict__ Cv,
    const float* __restrict__ bias, const float* __restrict__ res) {
  __shared__ __align__(16) u16 As[4][4096];
  __shared__ __align__(16) u16 Bs[4][2048];
  const int t = threadIdx.x;
  const int lane = t & 63;
  const int w = t >> 6;
  const int row0 = blockIdx.y * 128;
  const int col0 = blockIdx.x * 64;
  f32x4 acc[2][4];
#pragma unroll
  for (int i = 0; i < 2; ++i)
#pragma unroll
    for (int j = 0; j < 4; ++j) acc[i][j] = (f32x4){0.f, 0.f, 0.f, 0.f};

  GEMM_CORE

  const int q = lane >> 4, cl = lane & 15;
#pragma unroll
  for (int mt = 0; mt < 2; ++mt) {
#pragma unroll
    for (int nt = 0; nt < 4; ++nt) {
      int col = col0 + nt * 16 + cl;
#pragma unroll
      for (int r = 0; r < 4; ++r) {
        int row = row0 + (w * 2 + mt) * 16 + q * 4 + r;
        float v = acc[mt][nt][r];
        if (MODE == 1) {
          size_t idx = (size_t)row * 512 + col;
          ((float*)Cv)[idx] = v + res[idx];
        } else if (MODE == 2) {
          v += bias[col];
          ((u16*)Cv)[(size_t)row * 512 + col] = bf16rne(fmaxf(v, 0.f));
        } else {
          size_t idx = (size_t)row * 512 + col;
          ((float*)Cv)[idx] = v + bias[col] + res[idx];
        }
      }
    }
  }
}

// ---------------- merged projection GEMM: bx<8 -> Q (scaled SC2);
// bx>=8 -> fused K/V (V stored transposed into VT). grid (24, 64)
__global__ __launch_bounds__(256) void proj_kernel(
    const u16* __restrict__ Aq, const u16* __restrict__ BtQ, u16* __restrict__ Qp,
    const u16* __restrict__ Akv, const u16* __restrict__ BtKV,
    u16* __restrict__ Kp, u16* __restrict__ VTp) {
  __shared__ __align__(16) u16 As[4][4096];
  __shared__ __align__(16) u16 Bs[4][2048];
  const int t = threadIdx.x;
  const int lane = t & 63;
  const int w = t >> 6;
  const int bx = blockIdx.x;
  const bool isq = bx < 8;
  const u16* A = isq ? Aq : Akv;
  const u16* Bt = isq ? BtQ : BtKV;
  const int row0 = blockIdx.y * 128;
  const int col0 = (isq ? bx : bx - 8) * 64;
  f32x4 acc[2][4];
#pragma unroll
  for (int i = 0; i < 2; ++i)
#pragma unroll
    for (int j = 0; j < 4; ++j) acc[i][j] = (f32x4){0.f, 0.f, 0.f, 0.f};

  GEMM_CORE

  const int q = lane >> 4, cl = lane & 15;
#pragma unroll
  for (int mt = 0; mt < 2; ++mt) {
#pragma unroll
    for (int nt = 0; nt < 4; ++nt) {
      int col = col0 + nt * 16 + cl;
      if (!isq && col >= 512) {
        // V half: store transposed into VT[b][d][m], 4 m-rows packed
        int d = col - 512;
        int bb = row0 >> 12;
        int mloc = (row0 & 4095) + (w * 2 + mt) * 16 + q * 4;
        uint2 pk;
        pk.x = packrne(acc[mt][nt][0], acc[mt][nt][1]);
        pk.y = packrne(acc[mt][nt][2], acc[mt][nt][3]);
        *(uint2*)(VTp + ((size_t)bb * 512 + d) * 4096 + mloc) = pk;
        continue;
      }
#pragma unroll
      for (int r = 0; r < 4; ++r) {
        int row = row0 + (w * 2 + mt) * 16 + q * 4 + r;
        float v = acc[mt][nt][r];
        if (isq) {
          Qp[(size_t)row * 512 + col] = bf16rne(v * SC2);
        } else {
          Kp[(size_t)row * 512 + col] = bf16rne(v);
        }
      }
    }
  }
}

// ---------------- flash attention, S^T form, no-max softmax, split-kv=2.
// 128-thread blocks (2 waves); each wave owns 64 q columns; Bc=64.
__global__ __launch_bounds__(128, 2) void attn_kernel(
    const u16* __restrict__ Q, const u16* __restrict__ K,
    const u16* __restrict__ VT, u16* __restrict__ O0, u16* __restrict__ O1,
    float* __restrict__ lpart) {
  __shared__ __align__(16) u16 Ks[2][4096];
  __shared__ __align__(16) u16 Vs[2][4096];
  __shared__ __align__(16) u16 Ps[2][1024];
  const int t = threadIdx.x;
  const int lane = t & 63;
  const int w = t >> 6;
  const int g = lane >> 4, cl = lane & 15;
  const int qt = blockIdx.x, h = blockIdx.y;
  const int b = blockIdx.z >> 1, sp = blockIdx.z & 1;
  const u16* Qg = Q + ((size_t)(b * 4096 + qt * 128 + w * 64)) * 512 + h * 64;
  const u16* Kg = K + ((size_t)(b * 4096 + sp * 2048)) * 512 + h * 64;
  const u16* VTg = VT + ((size_t)(b * 512 + h * 64)) * 4096 + sp * 2048;
  u16* Ob = (sp ? O1 : O0) + (((size_t)(b * 8 + h) * 4096) + qt * 128 + w * 64) * 64;
  float* lb = lpart + ((size_t)((sp * 2 + b) * 8 + h)) * 4096 + qt * 128 + w * 64;
  char* Pw = (char*)Ps[w];

  // prologue: stage Q (wave-private, via Ks[w] scratch) -> registers
#pragma unroll
  for (int i = 0; i < 8; ++i) {
    async16(Qg + (size_t)((i >> 1) * 16 + cl) * 512 + (i & 1) * 32 + g * 8,
            (char*)Ks[w] + (i * 64 + lane) * 16);
  }
  vm_wait<0>();
  bf16x8 Qb[4][2];
#pragma unroll
  for (int nt = 0; nt < 4; ++nt)
#pragma unroll
    for (int ks = 0; ks < 2; ++ks)
      Qb[nt][ks] = *(const bf16x8*)((char*)Ks[w] + ((nt * 2 + ks) * 64 + lane) * 16);
  lgkm_wait0();
  bar();

#define STAGEKV(buf, m0)                                                          \
  {                                                                               \
    _Pragma("unroll") for (int i = 0; i < 4; ++i) {                               \
      int s = t + 128 * i; int c = s >> 6; int L = s & 63;                        \
      async16(Kg + (size_t)((m0) + (c >> 1) * 16 + (L & 15)) * 512 + (c & 1) * 32 + (L >> 4) * 8, \
              (char*)Ks[buf] + s * 16);                                           \
    }                                                                             \
    _Pragma("unroll") for (int i = 0; i < 4; ++i) {                               \
      int s = t + 128 * i; int c = s >> 6; int L = s & 63;                        \
      async16(VTg + (size_t)((c >> 1) * 16 + (L & 15)) * 4096 + (m0) + (c & 1) * 32 + (L >> 4) * 8, \
              (char*)Vs[buf] + s * 16);                                           \
    }                                                                             \
  }

  STAGEKV(0, 0);

  u16x8 ou;
#pragma unroll
  for (int j = 0; j < 8; ++j) ou[j] = 0x3F80;
  bf16x8 ones = __builtin_bit_cast(bf16x8, ou);

  f32x4 Oa[4][4], ls[4];
#pragma unroll
  for (int i = 0; i < 4; ++i) {
    ls[i] = (f32x4){0.f, 0.f, 0.f, 0.f};
#pragma unroll
    for (int j = 0; j < 4; ++j) Oa[i][j] = (f32x4){0.f, 0.f, 0.f, 0.f};
  }
  const int s7 = cl & 7;

  for (int it = 0; it < 32; ++it) {
    if (it < 31) {
      STAGEKV((it + 1) & 1, (it + 1) * 64);
      vm_wait<8>();
    } else {
      vm_wait<0>();
    }
    bar();
    const u16* Kc = Ks[it & 1];
    const u16* Vc = Vs[it & 1];
    bf16x8 Kf[4][2], Vf[4][2];
#pragma unroll
    for (int mt = 0; mt < 4; ++mt)
#pragma unroll
      for (int ks = 0; ks < 2; ++ks) {
        Kf[mt][ks] = *(const bf16x8*)((const char*)Kc + ((mt * 2 + ks) * 64 + lane) * 16);
        Vf[mt][ks] = *(const bf16x8*)((const char*)Vc + ((mt * 2 + ks) * 64 + lane) * 16);
      }

#pragma unroll
    for (int nt = 0; nt < 4; ++nt) {
      f32x4 St[4];
#pragma unroll
      for (int mt = 0; mt < 4; ++mt) St[mt] = (f32x4){0.f, 0.f, 0.f, 0.f};
#pragma unroll
      for (int ks = 0; ks < 2; ++ks)
#pragma unroll
        for (int mt = 0; mt < 4; ++mt)
          St[mt] = __builtin_amdgcn_mfma_f32_16x16x32_bf16(Kf[mt][ks], Qb[nt][ks], St[mt], 0, 0, 0);

#pragma unroll
      for (int mt = 0; mt < 4; ++mt) {
        float p0 = __builtin_amdgcn_exp2f(St[mt][0]);
        float p1 = __builtin_amdgcn_exp2f(St[mt][1]);
        float p2 = __builtin_amdgcn_exp2f(St[mt][2]);
        float p3 = __builtin_amdgcn_exp2f(St[mt][3]);
        uint2 pk;
        pk.x = __builtin_amdgcn_perm(__float_as_uint(p1), __float_as_uint(p0), 0x07060302u);
        pk.y = __builtin_amdgcn_perm(__float_as_uint(p3), __float_as_uint(p2), 0x07060302u);
        *(uint2*)(Pw + cl * 128 + (((mt * 2 + (g >> 1)) ^ s7) << 4) + ((g & 1) << 3)) = pk;
      }
      bf16x8 Pb[2];
#pragma unroll
      for (int ks = 0; ks < 2; ++ks)
        Pb[ks] = *(const bf16x8*)(Pw + cl * 128 + (((ks * 4 + g) ^ s7) << 4));
      ls[nt] = __builtin_amdgcn_mfma_f32_16x16x32_bf16(ones, Pb[0], ls[nt], 0, 0, 0);
      ls[nt] = __builtin_amdgcn_mfma_f32_16x16x32_bf16(ones, Pb[1], ls[nt], 0, 0, 0);
#pragma unroll
      for (int ks = 0; ks < 2; ++ks)
#pragma unroll
        for (int mtd = 0; mtd < 4; ++mtd)
          Oa[mtd][nt] = __builtin_amdgcn_mfma_f32_16x16x32_bf16(Vf[mtd][ks], Pb[ks], Oa[mtd][nt], 0, 0, 0);
    }
    bar();
  }

#pragma unroll
  for (int nt = 0; nt < 4; ++nt) {
    int q = nt * 16 + cl;
#pragma unroll
    for (int mtd = 0; mtd < 4; ++mtd) {
      uint2 pk;
      pk.x = packrne(Oa[mtd][nt][0], Oa[mtd][nt][1]);
      pk.y = packrne(Oa[mtd][nt][2], Oa[mtd][nt][3]);
      *(uint2*)(Ob + (size_t)q * 64 + mtd * 16 + g * 4) = pk;
    }
    if (g == 0) lb[q] = ls[nt][0];
  }
}

// ---------------- combine: attn_out = (O0+O1)/(l0+l1), bf16 [8192][512]
__global__ __launch_bounds__(256) void combine_kernel(
    const u16* __restrict__ O0, const u16* __restrict__ O1,
    const float* __restrict__ lp, u16* __restrict__ out) {
  int idx = blockIdx.x * 256 + threadIdx.x;
  int dc = idx & 7;
  int q = (idx >> 3) & 4095;
  int h = (idx >> 15) & 7;
  int b = idx >> 18;
  size_t po = (((size_t)(b * 8 + h) * 4096) + q) * 64 + dc * 8;
  u16x8 a = *(const u16x8*)(O0 + po);
  u16x8 c = *(const u16x8*)(O1 + po);
  float l0 = lp[((size_t)(b * 8 + h)) * 4096 + q];
  float l1 = lp[((size_t)(16 + b * 8 + h)) * 4096 + q];
  float inv = 1.0f / (l0 + l1);
  u16x8 o;
#pragma unroll
  for (int j = 0; j < 8; ++j) o[j] = bf16rne((b2f(a[j]) + b2f(c[j])) * inv);
  *(u16x8*)(out + ((size_t)(b * 4096 + q)) * 512 + h * 64 + dc * 8) = o;
}

extern "C" void kernel_launch(void* const* d_in, const int* in_sizes, int n_in,
                              void* d_out, int out_size, void* d_ws, size_t ws_size,
                              hipStream_t stream) {
  const float* q0 = (const float*)d_in[0];
  const float* kv0 = (const float*)d_in[1];
  const float* nq_g = (const float*)d_in[2];
  const float* nq_b = (const float*)d_in[3];
  const float* nkv_g = (const float*)d_in[4];
  const float* nkv_b = (const float*)d_in[5];
  const float* Wq = (const float*)d_in[6];
  const float* Wk = (const float*)d_in[7];
  const float* Wv = (const float*)d_in[8];
  const float* Wr = (const float*)d_in[9];
  const float* mlp_g = (const float*)d_in[10];
  const float* mlp_b = (const float*)d_in[11];
  const float* W1 = (const float*)d_in[12];
  const float* b1 = (const float*)d_in[13];
  const float* W2 = (const float*)d_in[14];
  const float* b2 = (const float*)d_in[15];
  float* out = (float*)d_out;

  // ws layout (phase-overlapped, ~61 MB high-water)
  char* ws = (char*)d_ws;
  float* ob = (float*)(ws + 0);
  u16* O1p = (u16*)(ws + 0);
  u16* Qp = (u16*)(ws + 16777216);
  u16* aout = (u16*)(ws + 16777216);
  u16* Kp = (u16*)(ws + 25165824);
  u16* h1 = (u16*)(ws + 25165824);
  u16* VTp = (u16*)(ws + 33554432);
  u16* kvn2 = (u16*)(ws + 33554432);
  u16* wb = (u16*)(ws + 41943040);
  float* lpart = (float*)(ws + 45088768);
  u16* qn = (u16*)(ws + 46137344);
  u16* O0p = (u16*)(ws + 46137344);
  u16* kvn = (u16*)(ws + 54525952);
  u16* wqT = wb;
  u16* wkT = wb + 262144;  // WkT rows 0-511, WvT rows 512-1023 (contiguous)
  u16* wrT = wb + 786432;
  u16* w1T = wb + 1048576;
  u16* w2T = wb + 1310720;

  dim3 blk(256);
  prep_kernel<<<4480, blk, 0, stream>>>(Wq, Wk, Wv, Wr, W1, W2, wb,
                                        q0, nq_g, nq_b, qn, kv0, nkv_g, nkv_b, kvn);
  proj_kernel<<<dim3(24, 64), blk, 0, stream>>>(qn, wqT, Qp, kvn, wkT, Kp, VTp);
  attn_kernel<<<dim3(32, 8, 4), dim3(128), 0, stream>>>(Qp, Kp, VTp, O0p, O1p, lpart);
  combine_kernel<<<2048, blk, 0, stream>>>(O0p, O1p, lpart, aout);
  gemm512_kernel<1><<<dim3(8, 64), blk, 0, stream>>>(aout, wrT, ob, nullptr, q0);
  ln_kernel<<<2048, blk, 0, stream>>>(ob, mlp_g, mlp_b, kvn2);
  gemm512_kernel<2><<<dim3(8, 64), blk, 0, stream>>>(kvn2, w1T, h1, b1, nullptr);
  gemm512_kernel<3><<<dim3(8, 64), blk, 0, stream>>>(h1, w2T, out, b2, ob);
}

// Round 6
// 286.445 us; speedup vs baseline: 1.0340x; 1.0340x over previous
//
#include <hip/hip_runtime.h>

typedef unsigned short u16;
typedef unsigned int u32;
typedef __bf16 bf16x8 __attribute__((ext_vector_type(8)));
typedef float f32x4 __attribute__((ext_vector_type(4)));
typedef u16 u16x8 __attribute__((ext_vector_type(8)));

#define SC2 0.18033688011112042f /* 0.125 * log2(e) */

__device__ __forceinline__ u16 bf16rne(float f) {
  u32 u = __float_as_uint(f);
  u32 r = (u + 0x7FFFu + ((u >> 16) & 1u)) >> 16;
  return (u16)r;
}
__device__ __forceinline__ u32 packrne(float a, float b) {
  return (u32)bf16rne(a) | ((u32)bf16rne(b) << 16);
}
__device__ __forceinline__ float b2f(u16 v) {
  return __uint_as_float(((u32)v) << 16);
}

__device__ __forceinline__ void async16(const void* g, void* l) {
  __builtin_amdgcn_global_load_lds(
      (__attribute__((address_space(1))) void*)(g),
      (__attribute__((address_space(3))) void*)(l), 16, 0, 0);
}
template <int N>
__device__ __forceinline__ void vm_wait() {
  asm volatile("s_waitcnt vmcnt(%0)" ::"n"(N) : "memory");
}
__device__ __forceinline__ void lgkm_wait0() {
  asm volatile("s_waitcnt lgkmcnt(0)" ::: "memory");
}
__device__ __forceinline__ void bar() {
  asm volatile("s_barrier" ::: "memory");
}

// ---------------- layernorm bodies (one wave per 512-row)
__device__ __forceinline__ void ln_row(const float* xr, const float* gp,
                                       const float* bp, u16* orow, int lane) {
  const float* xl = xr + lane * 8;
  float4 a0 = *(const float4*)xl;
  float4 a1 = *(const float4*)(xl + 4);
  float v[8] = {a0.x, a0.y, a0.z, a0.w, a1.x, a1.y, a1.z, a1.w};
  float s = 0.f, s2 = 0.f;
#pragma unroll
  for (int j = 0; j < 8; ++j) { s += v[j]; s2 += v[j] * v[j]; }
#pragma unroll
  for (int off = 32; off; off >>= 1) {
    s += __shfl_xor(s, off);
    s2 += __shfl_xor(s2, off);
  }
  float mu = s * (1.0f / 512.0f);
  float rstd = rsqrtf(s2 * (1.0f / 512.0f) - mu * mu + 1e-5f);
  const float* gl = gp + lane * 8;
  const float* bl = bp + lane * 8;
  float4 g0 = *(const float4*)gl, g1 = *(const float4*)(gl + 4);
  float4 b0 = *(const float4*)bl, b1 = *(const float4*)(bl + 4);
  float gg[8] = {g0.x, g0.y, g0.z, g0.w, g1.x, g1.y, g1.z, g1.w};
  float bb[8] = {b0.x, b0.y, b0.z, b0.w, b1.x, b1.y, b1.z, b1.w};
  u16x8 ov;
#pragma unroll
  for (int j = 0; j < 8; ++j) ov[j] = bf16rne((v[j] - mu) * rstd * gg[j] + bb[j]);
  *(u16x8*)(orow + lane * 8) = ov;
}

__device__ __forceinline__ void lnb_row(const u16* xr, const float* gp,
                                        const float* bp, u16* orow, int lane) {
  u16x8 xv = *(const u16x8*)(xr + lane * 8);
  float v[8];
#pragma unroll
  for (int j = 0; j < 8; ++j) v[j] = b2f(xv[j]);
  float s = 0.f, s2 = 0.f;
#pragma unroll
  for (int j = 0; j < 8; ++j) { s += v[j]; s2 += v[j] * v[j]; }
#pragma unroll
  for (int off = 32; off; off >>= 1) {
    s += __shfl_xor(s, off);
    s2 += __shfl_xor(s2, off);
  }
  float mu = s * (1.0f / 512.0f);
  float rstd = rsqrtf(s2 * (1.0f / 512.0f) - mu * mu + 1e-5f);
  const float* gl = gp + lane * 8;
  const float* bl = bp + lane * 8;
  float4 g0 = *(const float4*)gl, g1 = *(const float4*)(gl + 4);
  float4 b0 = *(const float4*)bl, b1 = *(const float4*)(bl + 4);
  float gg[8] = {g0.x, g0.y, g0.z, g0.w, g1.x, g1.y, g1.z, g1.w};
  float bb[8] = {b0.x, b0.y, b0.z, b0.w, b1.x, b1.y, b1.z, b1.w};
  u16x8 ov;
#pragma unroll
  for (int j = 0; j < 8; ++j) ov[j] = bf16rne((v[j] - mu) * rstd * gg[j] + bb[j]);
  *(u16x8*)(orow + lane * 8) = ov;
}

// ---------------- prep: blocks 0..383 = weight transpose (6 x 64 tiles),
// blocks 384..4479 = merged LN of q0 (rows<8192) and kv0
__global__ __launch_bounds__(256) void prep_kernel(
    const float* __restrict__ w0, const float* __restrict__ w1,
    const float* __restrict__ w2, const float* __restrict__ w3,
    const float* __restrict__ w4, const float* __restrict__ w5,
    u16* __restrict__ wout,
    const float* __restrict__ x0, const float* __restrict__ g0,
    const float* __restrict__ b0, u16* __restrict__ o0,
    const float* __restrict__ x1, const float* __restrict__ g1,
    const float* __restrict__ b1, u16* __restrict__ o1) {
  __shared__ u16 T[64 * 72];
  int t = threadIdx.x;
  int bx = blockIdx.x;
  if (bx < 384) {
    int widx = bx >> 6, tile = bx & 63;
    int k0 = (tile & 7) * 64, n0 = (tile >> 3) * 64;
    const float* W = w0;
    if (widx == 1) W = w1; else if (widx == 2) W = w2; else if (widx == 3) W = w3;
    else if (widx == 4) W = w4; else if (widx == 5) W = w5;
#pragma unroll
    for (int p = 0; p < 4; ++p) {
      int kr = p * 16 + (t >> 4);
      int nc = (t & 15) * 4;
      float4 v = *(const float4*)(W + (size_t)(k0 + kr) * 512 + n0 + nc);
      T[(nc + 0) * 72 + kr] = bf16rne(v.x);
      T[(nc + 1) * 72 + kr] = bf16rne(v.y);
      T[(nc + 2) * 72 + kr] = bf16rne(v.z);
      T[(nc + 3) * 72 + kr] = bf16rne(v.w);
    }
    __syncthreads();
    u16* ob = wout + (size_t)widx * 262144;
#pragma unroll
    for (int p = 0; p < 2; ++p) {
      int idx = p * 256 + t;
      int nr = idx >> 3, ch = idx & 7;
      uint4 val = *(const uint4*)(T + nr * 72 + ch * 8);
      *(uint4*)(ob + (size_t)(n0 + nr) * 512 + k0 + ch * 8) = val;
    }
  } else {
    int w = t >> 6, lane = t & 63;
    size_t row = (size_t)(bx - 384) * 4 + w;
    if (row < 8192) {
      ln_row(x0 + row * 512, g0, b0, o0 + row * 512, lane);
    } else {
      size_t r2 = row - 8192;
      ln_row(x1 + r2 * 512, g1, b1, o1 + r2 * 512, lane);
    }
  }
}

__global__ __launch_bounds__(256) void lnb_kernel(
    const u16* __restrict__ x, const float* __restrict__ g,
    const float* __restrict__ b, u16* __restrict__ o) {
  int w = threadIdx.x >> 6, lane = threadIdx.x & 63;
  size_t row = (size_t)blockIdx.x * 4 + w;
  lnb_row(x + row * 512, g, b, o + row * 512, lane);
}

// shared staging macro: 128x32 A-tile + 64x32 B-tile, 3 DMAs/thread
#define GSTAGE(buf, k0)                                                          \
  {                                                                              \
    _Pragma("unroll") for (int i = 0; i < 2; ++i) {                              \
      int s = t + 256 * i;                                                       \
      int mts = s >> 6, L = s & 63;                                             \
      async16(A + (size_t)(row0 + mts * 16 + (L & 15)) * 512 + (k0) + (L >> 4) * 8, \
              (char*)As[buf] + s * 16);                                          \
    }                                                                            \
    {                                                                            \
      int s = t;                                                                 \
      int nts = s >> 6, L = s & 63;                                             \
      async16(Bt + (size_t)(col0 + nts * 16 + (L & 15)) * 512 + (k0) + (L >> 4) * 8, \
              (char*)Bs[buf] + s * 16);                                          \
    }                                                                            \
  }

// 4-deep pipelined K-loop (prefetch 3 tiles, 1 barrier/iter) + 8 MFMAs/wave
#define GEMM_CORE                                                                \
  GSTAGE(0, 0);                                                                  \
  GSTAGE(1, 32);                                                                 \
  GSTAGE(2, 64);                                                                 \
  _Pragma("unroll") for (int kk = 0; kk < 16; ++kk) {                            \
    if (kk <= 13) vm_wait<6>();                                                  \
    else if (kk == 14) vm_wait<3>();                                             \
    else vm_wait<0>();                                                           \
    bar();                                                                       \
    if (kk < 13) GSTAGE((kk + 3) & 3, (kk + 3) * 32);                            \
    const u16* Ac = As[kk & 3];                                                  \
    const u16* Bc = Bs[kk & 3];                                                  \
    bf16x8 Af[2], Bf[4];                                                         \
    _Pragma("unroll") for (int mt = 0; mt < 2; ++mt)                             \
        Af[mt] = *(const bf16x8*)(Ac + ((w * 2 + mt) * 64 + lane) * 8);          \
    _Pragma("unroll") for (int nt = 0; nt < 4; ++nt)                             \
        Bf[nt] = *(const bf16x8*)(Bc + (nt * 64 + lane) * 8);                    \
    _Pragma("unroll") for (int mt = 0; mt < 2; ++mt)                             \
        _Pragma("unroll") for (int nt = 0; nt < 4; ++nt)                         \
            acc[mt][nt] = __builtin_amdgcn_mfma_f32_16x16x32_bf16(               \
                Af[mt], Bf[nt], acc[mt][nt], 0, 0, 0);                           \
  }

// ---------------- GEMM: C[8192,512] = A[8192,512](bf16) @ Bt[n][k](bf16)
// 128x64 tile, 4 waves. Grid (row=64, col=8): bid%8 = row%8 -> all col-tiles
// of one A-row-block land on ONE XCD (L2-resident A, no cross-XCD re-fetch).
// MODE 2: +bias relu bf16; 3: +bias f32 + bf16-res (res cast u16*);
// 7: bf16 out = v + f32 res
template <int MODE>
__global__ __launch_bounds__(256) void gemm512_kernel(
    const u16* __restrict__ A, const u16* __restrict__ Bt, void* __restrict__ Cv,
    const float* __restrict__ bias, const float* __restrict__ res) {
  __shared__ __align__(16) u16 As[4][4096];
  __shared__ __align__(16) u16 Bs[4][2048];
  const int t = threadIdx.x;
  const int lane = t & 63;
  const int w = t >> 6;
  const int row0 = blockIdx.x * 128;   // x = row-block: XCD colocation
  const int col0 = blockIdx.y * 64;
  f32x4 acc[2][4];
#pragma unroll
  for (int i = 0; i < 2; ++i)
#pragma unroll
    for (int j = 0; j < 4; ++j) acc[i][j] = (f32x4){0.f, 0.f, 0.f, 0.f};

  GEMM_CORE

  const int q = lane >> 4, cl = lane & 15;
#pragma unroll
  for (int mt = 0; mt < 2; ++mt) {
#pragma unroll
    for (int nt = 0; nt < 4; ++nt) {
      int col = col0 + nt * 16 + cl;
#pragma unroll
      for (int r = 0; r < 4; ++r) {
        int row = row0 + (w * 2 + mt) * 16 + q * 4 + r;
        float v = acc[mt][nt][r];
        size_t idx = (size_t)row * 512 + col;
        if (MODE == 2) {
          v += bias[col];
          ((u16*)Cv)[idx] = bf16rne(fmaxf(v, 0.f));
        } else if (MODE == 3) {
          ((float*)Cv)[idx] = v + bias[col] + b2f(((const u16*)res)[idx]);
        } else if (MODE == 7) {
          ((u16*)Cv)[idx] = bf16rne(v + res[idx]);
        }
      }
    }
  }
}

// ---------------- merged projection GEMM: grid (row=64, col=24);
// col<8 -> Q (scaled SC2); col>=8 -> fused K/V (V stored transposed to VT)
__global__ __launch_bounds__(256) void proj_kernel(
    const u16* __restrict__ Aq, const u16* __restrict__ BtQ, u16* __restrict__ Qp,
    const u16* __restrict__ Akv, const u16* __restrict__ BtKV,
    u16* __restrict__ Kp, u16* __restrict__ VTp) {
  __shared__ __align__(16) u16 As[4][4096];
  __shared__ __align__(16) u16 Bs[4][2048];
  const int t = threadIdx.x;
  const int lane = t & 63;
  const int w = t >> 6;
  const int by = blockIdx.y;
  const bool isq = by < 8;
  const u16* A = isq ? Aq : Akv;
  const u16* Bt = isq ? BtQ : BtKV;
  const int row0 = blockIdx.x * 128;   // x = row-block: XCD colocation
  const int col0 = (isq ? by : by - 8) * 64;
  f32x4 acc[2][4];
#pragma unroll
  for (int i = 0; i < 2; ++i)
#pragma unroll
    for (int j = 0; j < 4; ++j) acc[i][j] = (f32x4){0.f, 0.f, 0.f, 0.f};

  GEMM_CORE

  const int q = lane >> 4, cl = lane & 15;
#pragma unroll
  for (int mt = 0; mt < 2; ++mt) {
#pragma unroll
    for (int nt = 0; nt < 4; ++nt) {
      int col = col0 + nt * 16 + cl;
      if (!isq && col >= 512) {
        // V half: store transposed into VT[b][d][m], 4 m-rows packed
        int d = col - 512;
        int bb = row0 >> 12;
        int mloc = (row0 & 4095) + (w * 2 + mt) * 16 + q * 4;
        uint2 pk;
        pk.x = packrne(acc[mt][nt][0], acc[mt][nt][1]);
        pk.y = packrne(acc[mt][nt][2], acc[mt][nt][3]);
        *(uint2*)(VTp + ((size_t)bb * 512 + d) * 4096 + mloc) = pk;
        continue;
      }
#pragma unroll
      for (int r = 0; r < 4; ++r) {
        int row = row0 + (w * 2 + mt) * 16 + q * 4 + r;
        float v = acc[mt][nt][r];
        if (isq) {
          Qp[(size_t)row * 512 + col] = bf16rne(v * SC2);
        } else {
          Kp[(size_t)row * 512 + col] = bf16rne(v);
        }
      }
    }
  }
}

// ---------------- flash attention, S^T form, no-max softmax, split-kv=2.
// Grid (h=8, qt=32, bz=4): bid%8 = h -> each head's K/V slices (<=2MB) stay
// resident in ONE XCD's L2. 128-thread blocks (2 waves); wave owns 64 q cols.
__global__ __launch_bounds__(128, 2) void attn_kernel(
    const u16* __restrict__ Q, const u16* __restrict__ K,
    const u16* __restrict__ VT, u16* __restrict__ O0, u16* __restrict__ O1,
    float* __restrict__ lpart) {
  __shared__ __align__(16) u16 Ks[2][4096];
  __shared__ __align__(16) u16 Vs[2][4096];
  __shared__ __align__(16) u16 Ps[2][1024];
  const int t = threadIdx.x;
  const int lane = t & 63;
  const int w = t >> 6;
  const int g = lane >> 4, cl = lane & 15;
  const int h = blockIdx.x, qt = blockIdx.y;
  const int b = blockIdx.z >> 1, sp = blockIdx.z & 1;
  const u16* Qg = Q + ((size_t)(b * 4096 + qt * 128 + w * 64)) * 512 + h * 64;
  const u16* Kg = K + ((size_t)(b * 4096 + sp * 2048)) * 512 + h * 64;
  const u16* VTg = VT + ((size_t)(b * 512 + h * 64)) * 4096 + sp * 2048;
  u16* Ob = (sp ? O1 : O0) + (((size_t)(b * 8 + h) * 4096) + qt * 128 + w * 64) * 64;
  float* lb = lpart + ((size_t)((sp * 2 + b) * 8 + h)) * 4096 + qt * 128 + w * 64;
  char* Pw = (char*)Ps[w];

  // prologue: stage Q (wave-private, via Ks[w] scratch) -> registers
#pragma unroll
  for (int i = 0; i < 8; ++i) {
    async16(Qg + (size_t)((i >> 1) * 16 + cl) * 512 + (i & 1) * 32 + g * 8,
            (char*)Ks[w] + (i * 64 + lane) * 16);
  }
  vm_wait<0>();
  bf16x8 Qb[4][2];
#pragma unroll
  for (int nt = 0; nt < 4; ++nt)
#pragma unroll
    for (int ks = 0; ks < 2; ++ks)
      Qb[nt][ks] = *(const bf16x8*)((char*)Ks[w] + ((nt * 2 + ks) * 64 + lane) * 16);
  lgkm_wait0();
  bar();

#define STAGEKV(buf, m0)                                                          \
  {                                                                               \
    _Pragma("unroll") for (int i = 0; i < 4; ++i) {                               \
      int s = t + 128 * i; int c = s >> 6; int L = s & 63;                        \
      async16(Kg + (size_t)((m0) + (c >> 1) * 16 + (L & 15)) * 512 + (c & 1) * 32 + (L >> 4) * 8, \
              (char*)Ks[buf] + s * 16);                                           \
    }                                                                             \
    _Pragma("unroll") for (int i = 0; i < 4; ++i) {                               \
      int s = t + 128 * i; int c = s >> 6; int L = s & 63;                        \
      async16(VTg + (size_t)((c >> 1) * 16 + (L & 15)) * 4096 + (m0) + (c & 1) * 32 + (L >> 4) * 8, \
              (char*)Vs[buf] + s * 16);                                           \
    }                                                                             \
  }

  STAGEKV(0, 0);

  u16x8 ou;
#pragma unroll
  for (int j = 0; j < 8; ++j) ou[j] = 0x3F80;
  bf16x8 ones = __builtin_bit_cast(bf16x8, ou);

  f32x4 Oa[4][4], ls[4];
#pragma unroll
  for (int i = 0; i < 4; ++i) {
    ls[i] = (f32x4){0.f, 0.f, 0.f, 0.f};
#pragma unroll
    for (int j = 0; j < 4; ++j) Oa[i][j] = (f32x4){0.f, 0.f, 0.f, 0.f};
  }
  const int s7 = cl & 7;

  for (int it = 0; it < 32; ++it) {
    if (it < 31) {
      STAGEKV((it + 1) & 1, (it + 1) * 64);
      vm_wait<8>();
    } else {
      vm_wait<0>();
    }
    bar();
    const u16* Kc = Ks[it & 1];
    const u16* Vc = Vs[it & 1];
    bf16x8 Kf[4][2], Vf[4][2];
#pragma unroll
    for (int mt = 0; mt < 4; ++mt)
#pragma unroll
      for (int ks = 0; ks < 2; ++ks) {
        Kf[mt][ks] = *(const bf16x8*)((const char*)Kc + ((mt * 2 + ks) * 64 + lane) * 16);
        Vf[mt][ks] = *(const bf16x8*)((const char*)Vc + ((mt * 2 + ks) * 64 + lane) * 16);
      }

#pragma unroll
    for (int nt = 0; nt < 4; ++nt) {
      f32x4 St[4];
#pragma unroll
      for (int mt = 0; mt < 4; ++mt) St[mt] = (f32x4){0.f, 0.f, 0.f, 0.f};
#pragma unroll
      for (int ks = 0; ks < 2; ++ks)
#pragma unroll
        for (int mt = 0; mt < 4; ++mt)
          St[mt] = __builtin_amdgcn_mfma_f32_16x16x32_bf16(Kf[mt][ks], Qb[nt][ks], St[mt], 0, 0, 0);

#pragma unroll
      for (int mt = 0; mt < 4; ++mt) {
        float p0 = __builtin_amdgcn_exp2f(St[mt][0]);
        float p1 = __builtin_amdgcn_exp2f(St[mt][1]);
        float p2 = __builtin_amdgcn_exp2f(St[mt][2]);
        float p3 = __builtin_amdgcn_exp2f(St[mt][3]);
        uint2 pk;
        pk.x = __builtin_amdgcn_perm(__float_as_uint(p1), __float_as_uint(p0), 0x07060302u);
        pk.y = __builtin_amdgcn_perm(__float_as_uint(p3), __float_as_uint(p2), 0x07060302u);
        *(uint2*)(Pw + cl * 128 + (((mt * 2 + (g >> 1)) ^ s7) << 4) + ((g & 1) << 3)) = pk;
      }
      bf16x8 Pb[2];
#pragma unroll
      for (int ks = 0; ks < 2; ++ks)
        Pb[ks] = *(const bf16x8*)(Pw + cl * 128 + (((ks * 4 + g) ^ s7) << 4));
      ls[nt] = __builtin_amdgcn_mfma_f32_16x16x32_bf16(ones, Pb[0], ls[nt], 0, 0, 0);
      ls[nt] = __builtin_amdgcn_mfma_f32_16x16x32_bf16(ones, Pb[1], ls[nt], 0, 0, 0);
#pragma unroll
      for (int ks = 0; ks < 2; ++ks)
#pragma unroll
        for (int mtd = 0; mtd < 4; ++mtd)
          Oa[mtd][nt] = __builtin_amdgcn_mfma_f32_16x16x32_bf16(Vf[mtd][ks], Pb[ks], Oa[mtd][nt], 0, 0, 0);
    }
    bar();
  }

#pragma unroll
  for (int nt = 0; nt < 4; ++nt) {
    int q = nt * 16 + cl;
#pragma unroll
    for (int mtd = 0; mtd < 4; ++mtd) {
      uint2 pk;
      pk.x = packrne(Oa[mtd][nt][0], Oa[mtd][nt][1]);
      pk.y = packrne(Oa[mtd][nt][2], Oa[mtd][nt][3]);
      *(uint2*)(Ob + (size_t)q * 64 + mtd * 16 + g * 4) = pk;
    }
    if (g == 0) lb[q] = ls[nt][0];
  }
}

// ---------------- combine: attn_out = (O0+O1)/(l0+l1), bf16 [8192][512]
__global__ __launch_bounds__(256) void combine_kernel(
    const u16* __restrict__ O0, const u16* __restrict__ O1,
    const float* __restrict__ lp, u16* __restrict__ out) {
  int idx = blockIdx.x * 256 + threadIdx.x;
  int dc = idx & 7;
  int q = (idx >> 3) & 4095;
  int h = (idx >> 15) & 7;
  int b = idx >> 18;
  size_t po = (((size_t)(b * 8 + h) * 4096) + q) * 64 + dc * 8;
  u16x8 a = *(const u16x8*)(O0 + po);
  u16x8 c = *(const u16x8*)(O1 + po);
  float l0 = lp[((size_t)(b * 8 + h)) * 4096 + q];
  float l1 = lp[((size_t)(16 + b * 8 + h)) * 4096 + q];
  float inv = 1.0f / (l0 + l1);
  u16x8 o;
#pragma unroll
  for (int j = 0; j < 8; ++j) o[j] = bf16rne((b2f(a[j]) + b2f(c[j])) * inv);
  *(u16x8*)(out + ((size_t)(b * 4096 + q)) * 512 + h * 64 + dc * 8) = o;
}

extern "C" void kernel_launch(void* const* d_in, const int* in_sizes, int n_in,
                              void* d_out, int out_size, void* d_ws, size_t ws_size,
                              hipStream_t stream) {
  const float* q0 = (const float*)d_in[0];
  const float* kv0 = (const float*)d_in[1];
  const float* nq_g = (const float*)d_in[2];
  const float* nq_b = (const float*)d_in[3];
  const float* nkv_g = (const float*)d_in[4];
  const float* nkv_b = (const float*)d_in[5];
  const float* Wq = (const float*)d_in[6];
  const float* Wk = (const float*)d_in[7];
  const float* Wv = (const float*)d_in[8];
  const float* Wr = (const float*)d_in[9];
  const float* mlp_g = (const float*)d_in[10];
  const float* mlp_b = (const float*)d_in[11];
  const float* W1 = (const float*)d_in[12];
  const float* b1 = (const float*)d_in[13];
  const float* W2 = (const float*)d_in[14];
  const float* b2 = (const float*)d_in[15];
  float* out = (float*)d_out;

  // ws layout (phase-overlapped, ~61 MB high-water)
  char* ws = (char*)d_ws;
  u16* obb = (u16*)(ws + 0);           // bf16 residual stream (after gemm<7>)
  u16* O1p = (u16*)(ws + 0);           // O1 partial (dead before obb written)
  u16* Qp = (u16*)(ws + 16777216);
  u16* aout = (u16*)(ws + 16777216);
  u16* Kp = (u16*)(ws + 25165824);
  u16* h1 = (u16*)(ws + 25165824);
  u16* VTp = (u16*)(ws + 33554432);
  u16* kvn2 = (u16*)(ws + 33554432);
  u16* wb = (u16*)(ws + 41943040);
  float* lpart = (float*)(ws + 45088768);
  u16* qn = (u16*)(ws + 46137344);
  u16* O0p = (u16*)(ws + 46137344);
  u16* kvn = (u16*)(ws + 54525952);
  u16* wqT = wb;
  u16* wkT = wb + 262144;  // WkT rows 0-511, WvT rows 512-1023 (contiguous)
  u16* wrT = wb + 786432;
  u16* w1T = wb + 1048576;
  u16* w2T = wb + 1310720;

  dim3 blk(256);
  prep_kernel<<<4480, blk, 0, stream>>>(Wq, Wk, Wv, Wr, W1, W2, wb,
                                        q0, nq_g, nq_b, qn, kv0, nkv_g, nkv_b, kvn);
  proj_kernel<<<dim3(64, 24), blk, 0, stream>>>(qn, wqT, Qp, kvn, wkT, Kp, VTp);
  attn_kernel<<<dim3(8, 32, 4), dim3(128), 0, stream>>>(Qp, Kp, VTp, O0p, O1p, lpart);
  combine_kernel<<<2048, blk, 0, stream>>>(O0p, O1p, lpart, aout);
  gemm512_kernel<7><<<dim3(64, 8), blk, 0, stream>>>(aout, wrT, obb, nullptr, q0);
  lnb_kernel<<<2048, blk, 0, stream>>>(obb, mlp_g, mlp_b, kvn2);
  gemm512_kernel<2><<<dim3(64, 8), blk, 0, stream>>>(kvn2, w1T, h1, b1, nullptr);
  gemm512_kernel<3><<<dim3(64, 8), blk, 0, stream>>>(h1, w2T, out, b2, (const float*)obb);
}